// Round 2
// baseline (3907.320 us; speedup 1.0000x reference)
//
#include <hip/hip_runtime.h>
#include <hip/hip_bf16.h>

#define FP const float* __restrict__

__device__ __forceinline__ float sp(float x) {            // numerically-stable softplus
    return fmaxf(x, 0.f) + log1pf(expf(-fabsf(x)));
}
__device__ __forceinline__ float silu_f(float x) { return x / (1.f + expf(-x)); }

// ---------------------------------------------------------------------------
// K1: per-edge attention logits alpha0[e][h] = softplus(sum(concat(hi,hj)*att))
//     hi = softplus(xi@W), hj = softplus(xj@W); xi=[atom[row],ef], xj=[atom[col],ef]
//     Also accumulates BN stats (sum, sumsq per head) via LDS->global atomics.
// 32 lanes per edge, each lane owns 4 consecutive output columns (o0=4*lt).
// ---------------------------------------------------------------------------
__global__ __launch_bounds__(256) void k1_alpha(
    FP atom, const int* __restrict__ eidx, FP efea, FP Wg, FP attg,
    float* __restrict__ alpha, float* __restrict__ bnstat, int E)
{
    __shared__ __align__(16) float Wl[64 * 128];   // 32 KB
    __shared__ __align__(16) float attl[256];
    __shared__ float xs[8][3][32];                 // per group: atom_i, atom_j, ef
    __shared__ float bnl[8];
    const int t = threadIdx.x;
    for (int r = t; r < 2048; r += 256) ((float4*)Wl)[r] = ((const float4*)Wg)[r];
    if (t < 64) ((float4*)attl)[t] = ((const float4*)attg)[t];
    if (t < 8) bnl[t] = 0.f;
    __syncthreads();

    const int g  = t >> 5;        // edge-group 0..7
    const int lt = t & 31;        // lane in group
    const int o0 = lt * 4;        // output cols o0..o0+3
    const int hh = lt >> 3;       // head of this lane's columns

    for (int base = blockIdx.x * 8; base < E; base += gridDim.x * 8) {
        const int e = base + g;
        const bool act = (e < E);
        if (act) {
            const int i = eidx[e], j = eidx[E + e];
            xs[g][0][lt] = atom[i * 32 + lt];
            xs[g][1][lt] = atom[j * 32 + lt];
            xs[g][2][lt] = efea[e * 32 + lt];
        }
        __syncthreads();

        float4 ai = {0,0,0,0}, aj = {0,0,0,0}, ae = {0,0,0,0};
#pragma unroll
        for (int k = 0; k < 32; ++k) {
            const float xik = xs[g][0][k], xjk = xs[g][1][k], xek = xs[g][2][k];
            const float4 w0 = *(const float4*)&Wl[k * 128 + o0];
            const float4 w1 = *(const float4*)&Wl[(32 + k) * 128 + o0];
            ai.x += xik * w0.x; ai.y += xik * w0.y; ai.z += xik * w0.z; ai.w += xik * w0.w;
            aj.x += xjk * w0.x; aj.y += xjk * w0.y; aj.z += xjk * w0.z; aj.w += xjk * w0.w;
            ae.x += xek * w1.x; ae.y += xek * w1.y; ae.z += xek * w1.z; ae.w += xek * w1.w;
        }
        // attention dot for this lane's 4 columns
        const float* a1 = &attl[hh * 64 + (o0 & 31)];
        const float* a2 = a1 + 32;
        float part = 0.f;
        part += sp(ai.x + ae.x) * a1[0] + sp(aj.x + ae.x) * a2[0];
        part += sp(ai.y + ae.y) * a1[1] + sp(aj.y + ae.y) * a2[1];
        part += sp(ai.z + ae.z) * a1[2] + sp(aj.z + ae.z) * a2[2];
        part += sp(ai.w + ae.w) * a1[3] + sp(aj.w + ae.w) * a2[3];
        // reduce across the 8 lanes of this head
        part += __shfl_xor(part, 1);
        part += __shfl_xor(part, 2);
        part += __shfl_xor(part, 4);
        if (act && (lt & 7) == 0) {
            const float a0 = sp(part);
            alpha[e * 4 + hh] = a0;
            atomicAdd(&bnl[hh], a0);
            atomicAdd(&bnl[4 + hh], a0 * a0);
        }
        __syncthreads();  // protect xs before next overwrite
    }
    if (t < 8) atomicAdd(&bnstat[t], bnl[t]);
}

// K2: finalize BN: scale[h], shift[h]
__global__ void k2_bn(const float* __restrict__ bnstat, FP gam, FP bet,
                      float* __restrict__ bnsc, int E)
{
    const int t = threadIdx.x;
    if (t < 4) {
        const float inv = 1.f / (float)E;
        const float mu  = bnstat[t] * inv;
        const float var = bnstat[4 + t] * inv - mu * mu;
        const float scl = gam[t] * rsqrtf(var + 1e-5f);
        bnsc[t] = scl;
        bnsc[4 + t] = bet[t] - mu * scl;
    }
}

// K3: alpha1 = softplus(scale*alpha0+shift); segment max via uint atomicMax
__global__ __launch_bounds__(256) void k3_bnmax(
    float* __restrict__ alpha, const int* __restrict__ eidx,
    unsigned int* __restrict__ mbuf, const float* __restrict__ bnsc, int E)
{
    const int t = blockIdx.x * 256 + threadIdx.x;
    if (t >= 4 * E) return;
    const int e = t >> 2, h = t & 3;
    const float a1 = sp(bnsc[h] * alpha[t] + bnsc[4 + h]);
    alpha[t] = a1;
    atomicMax(&mbuf[eidx[e] * 4 + h], __float_as_uint(a1));   // a1>0 so uint order == float order
}

// K4: ex = exp(alpha1 - m[row]); segment sum
__global__ __launch_bounds__(256) void k4_exps(
    float* __restrict__ alpha, const int* __restrict__ eidx,
    const float* __restrict__ mbuf, float* __restrict__ sbuf, int E)
{
    const int t = blockIdx.x * 256 + threadIdx.x;
    if (t >= 4 * E) return;
    const int e = t >> 2, h = t & 3;
    const float ex = expf(alpha[t] - mbuf[eidx[e] * 4 + h]);
    alpha[t] = ex;
    atomicAdd(&sbuf[eidx[e] * 4 + h], ex);
}

// ---------------------------------------------------------------------------
// K5: recompute hj, collapse heads: contrib[f] = 0.25*sum_h softplus(hj[h,f])*alpha[h]
//     atomicAdd into acc[N][32]. 32 lanes/edge, 2 edges per lane share W reads.
// ---------------------------------------------------------------------------
__global__ __launch_bounds__(256) void k5_msg(
    FP atom, const int* __restrict__ eidx, FP efea, FP Wg,
    const float* __restrict__ alpha, const float* __restrict__ sbuf,
    float* __restrict__ accN, int E)
{
    __shared__ __align__(16) float Wl[64 * 128];
    __shared__ float xs[8][2][2][32];   // group, pair, {atom_j, ef}
    __shared__ float al[8][2][4];       // final alpha per edge/head
    const int t = threadIdx.x;
    for (int r = t; r < 2048; r += 256) ((float4*)Wl)[r] = ((const float4*)Wg)[r];
    __syncthreads();
    const int g = t >> 5, lt = t & 31;

    for (int base = blockIdx.x * 16; base < E; base += gridDim.x * 16) {
        const int e0 = base + g * 2;
#pragma unroll
        for (int p = 0; p < 2; ++p) {
            const int e = e0 + p;
            if (e < E) {
                const int j = eidx[E + e];
                xs[g][p][0][lt] = atom[j * 32 + lt];
                xs[g][p][1][lt] = efea[e * 32 + lt];
                if (lt < 4) {
                    const int r = eidx[e];
                    al[g][p][lt] = alpha[e * 4 + lt] / (sbuf[r * 4 + lt] + 1e-16f);
                }
            }
        }
        __syncthreads();

        float acc[2][4] = {{0,0,0,0},{0,0,0,0}};
#pragma unroll
        for (int k = 0; k < 32; ++k) {
            const float w0 = Wl[k*128 + lt],      w1 = Wl[k*128 + 32 + lt];
            const float w2 = Wl[k*128 + 64 + lt], w3 = Wl[k*128 + 96 + lt];
            const float v0 = Wl[(32+k)*128 + lt],      v1 = Wl[(32+k)*128 + 32 + lt];
            const float v2 = Wl[(32+k)*128 + 64 + lt], v3 = Wl[(32+k)*128 + 96 + lt];
#pragma unroll
            for (int p = 0; p < 2; ++p) {
                const float xa = xs[g][p][0][k], xe = xs[g][p][1][k];
                acc[p][0] += xa * w0; acc[p][0] += xe * v0;
                acc[p][1] += xa * w1; acc[p][1] += xe * v1;
                acc[p][2] += xa * w2; acc[p][2] += xe * v2;
                acc[p][3] += xa * w3; acc[p][3] += xe * v3;
            }
        }
#pragma unroll
        for (int p = 0; p < 2; ++p) {
            const int e = e0 + p;
            if (e < E) {
                float c = 0.f;
#pragma unroll
                for (int h = 0; h < 4; ++h) c += sp(acc[p][h]) * al[g][p][h];
                atomicAdd(&accN[eidx[e] * 32 + lt], 0.25f * c);
            }
        }
        __syncthreads();
    }
}

// K6: out = acc + bias (float out)
__global__ __launch_bounds__(256) void k6_out(
    const float* __restrict__ accN, FP bias, float* __restrict__ outp, int N)
{
    const int t = blockIdx.x * 256 + threadIdx.x;
    if (t < N * 32) outp[t] = accN[t] + bias[t & 31];
}

// ---------------------------------------------------------------------------
// K7: edge MLP: silu(silu([out[row],out[col],ef] @ W1 + b1) @ W2 + b2)
// 4 edges per block-iter; layer1: thread=(pair,o), 2 edges share each W1 read.
// ---------------------------------------------------------------------------
__global__ __launch_bounds__(256) void k7_mlp(
    const float* __restrict__ outp, const int* __restrict__ eidx, FP efea,
    FP W1g, FP b1g, FP W2g, FP b2g,
    float* __restrict__ eout, int E)
{
    __shared__ __align__(16) float W1l[96 * 128];  // 48 KB
    __shared__ __align__(16) float W2l[128 * 32];  // 16 KB
    __shared__ __align__(16) float b1l[128];
    __shared__ __align__(16) float b2l[32];
    __shared__ float inl[4][96];
    __shared__ float hidl[4][128];
    const int t = threadIdx.x;
    for (int r = t; r < 3072; r += 256) ((float4*)W1l)[r] = ((const float4*)W1g)[r];
    for (int r = t; r < 1024; r += 256) ((float4*)W2l)[r] = ((const float4*)W2g)[r];
    if (t < 32) ((float4*)b1l)[t] = ((const float4*)b1g)[t];
    if (t < 8)  ((float4*)b2l)[t] = ((const float4*)b2g)[t];
    __syncthreads();

    for (int base = blockIdx.x * 4; base < E; base += gridDim.x * 4) {
        for (int r = t; r < 4 * 96; r += 256) {
            const int eL = r / 96, k = r - eL * 96;
            const int e = base + eL;
            if (e < E) {
                float v;
                if (k < 32)      v = outp[eidx[e] * 32 + k];
                else if (k < 64) v = outp[eidx[E + e] * 32 + (k - 32)];
                else             v = efea[e * 32 + (k - 64)];
                inl[eL][k] = v;
            }
        }
        __syncthreads();
        {   // layer 1
            const int o = t & 127, p = t >> 7;
            const float* iA = inl[2 * p];
            const float* iB = inl[2 * p + 1];
            float a0 = b1l[o], a1 = 0.f, b0 = b1l[o], b1 = 0.f;
#pragma unroll 8
            for (int k = 0; k < 96; k += 2) {
                const float w0 = W1l[k * 128 + o];
                const float w1 = W1l[(k + 1) * 128 + o];
                a0 += iA[k] * w0;  a1 += iA[k + 1] * w1;
                b0 += iB[k] * w0;  b1 += iB[k + 1] * w1;
            }
            hidl[2 * p][o]     = silu_f(a0 + a1);
            hidl[2 * p + 1][o] = silu_f(b0 + b1);
        }
        __syncthreads();
        {   // layer 2
            const int eL = t >> 6, f = t & 31, half = (t >> 5) & 1;
            const float* hd = hidl[eL] + half * 64;
            float c0 = half ? 0.f : b2l[f], c1 = 0.f;
#pragma unroll 8
            for (int o = 0; o < 64; o += 2) {
                c0 += hd[o]     * W2l[(half * 64 + o) * 32 + f];
                c1 += hd[o + 1] * W2l[(half * 64 + o + 1) * 32 + f];
            }
            float acc = c0 + c1;
            acc += __shfl_xor(acc, 32);
            const int e = base + eL;
            if (half == 0 && e < E) eout[e * 32 + f] = silu_f(acc);
        }
        __syncthreads();
    }
}

extern "C" void kernel_launch(void* const* d_in, const int* in_sizes, int n_in,
                              void* d_out, int out_size, void* d_ws, size_t ws_size,
                              hipStream_t stream)
{
    const float* atom = (const float*)d_in[0];
    const int*   eidx = (const int*)d_in[1];
    const float* efea = (const float*)d_in[2];
    const float* Wg   = (const float*)d_in[6];
    const float* attg = (const float*)d_in[7];
    const float* bias = (const float*)d_in[8];
    const float* gam  = (const float*)d_in[9];
    const float* bet  = (const float*)d_in[10];
    const float* W1g  = (const float*)d_in[11];
    const float* b1g  = (const float*)d_in[12];
    const float* W2g  = (const float*)d_in[13];
    const float* b2g  = (const float*)d_in[14];

    const int N = in_sizes[0] / 32;
    const int E = in_sizes[2] / 32;

    float* ws     = (float*)d_ws;
    float* alpha  = ws;                           // 4E floats
    float* mbuf   = alpha + (size_t)4 * E;        // 4N
    float* sbuf   = mbuf + (size_t)4 * N;         // 4N
    float* accN   = sbuf + (size_t)4 * N;         // 32N
    float* bnstat = accN + (size_t)32 * N;        // 8
    float* bnsc   = bnstat + 8;                   // 8
    const size_t zero_bytes = ((size_t)(4 * N + 4 * N + 32 * N + 8)) * sizeof(float);
    hipMemsetAsync(mbuf, 0, zero_bytes, stream);  // m, s, acc, bnstat

    float* outp = (float*)d_out;
    float* eout = outp + (size_t)N * 32;

    const int n4e = 4 * E;
    k1_alpha<<<2048, 256, 0, stream>>>(atom, eidx, efea, Wg, attg, alpha, bnstat, E);
    k2_bn<<<1, 64, 0, stream>>>(bnstat, gam, bet, bnsc, E);
    k3_bnmax<<<(n4e + 255) / 256, 256, 0, stream>>>(alpha, eidx, (unsigned int*)mbuf, bnsc, E);
    k4_exps<<<(n4e + 255) / 256, 256, 0, stream>>>(alpha, eidx, mbuf, sbuf, E);
    k5_msg<<<2048, 256, 0, stream>>>(atom, eidx, efea, Wg, alpha, sbuf, accN, E);
    k6_out<<<(N * 32 + 255) / 256, 256, 0, stream>>>(accN, bias, outp, N);
    k7_mlp<<<2048, 256, 0, stream>>>(outp, eidx, efea, W1g, b1g, W2g, b2g, eout, E);
}

// Round 3
// 1680.077 us; speedup vs baseline: 2.3257x; 2.3257x over previous
//
#include <hip/hip_runtime.h>

typedef __attribute__((ext_vector_type(8))) short bf16x8;
typedef __attribute__((ext_vector_type(4))) float f32x4;

#define FP const float* __restrict__

__device__ __forceinline__ short f2bf(float f) {
    unsigned u = __float_as_uint(f);
    u += 0x7fffu + ((u >> 16) & 1u);
    return (short)(u >> 16);
}
__device__ __forceinline__ float bf2f(short s) {
    return __uint_as_float(((unsigned)(unsigned short)s) << 16);
}
__device__ __forceinline__ float sp(float x) {            // stable softplus
    return fmaxf(x, 0.f) + log1pf(expf(-fabsf(x)));
}
__device__ __forceinline__ float silu_f(float x) { return x / (1.f + expf(-x)); }

// A-operand = W^T tile: lane l holds W[k, c0+(l&15)], k = 8*(l>>4)+j. W is [32+,ld] f32.
__device__ __forceinline__ bf16x8 load_wfrag(FP w, int ld, int c0, int l) {
    const int c = c0 + (l & 15);
    const int k0 = 8 * (l >> 4);
    bf16x8 f;
#pragma unroll
    for (int j = 0; j < 8; ++j) f[j] = f2bf(w[(k0 + j) * ld + c]);
    return f;
}
// B-operand = x^T tile: lane l holds x[r0+(l&15), 8*(l>>4)+j]; x is [R,32] f32 row-major.
__device__ __forceinline__ bf16x8 load_xfrag32(FP x, int r0, int l, int R) {
    int row = r0 + (l & 15);
    row = row < R ? row : R - 1;
    const float* p = x + (size_t)row * 32 + 8 * (l >> 4);
    const float4 a = *(const float4*)p;
    const float4 b = *(const float4*)(p + 4);
    bf16x8 f;
    f[0]=f2bf(a.x); f[1]=f2bf(a.y); f[2]=f2bf(a.z); f[3]=f2bf(a.w);
    f[4]=f2bf(b.x); f[5]=f2bf(b.y); f[6]=f2bf(b.z); f[7]=f2bf(b.w);
    return f;
}

// ---------------------------------------------------------------------------
// kA: A = bf16(atom @ Wa)  [N,128].  swapped-form MFMA, 16 nodes/wave-tile.
// ---------------------------------------------------------------------------
__global__ __launch_bounds__(256) void kA(FP x, FP W0, short* __restrict__ Aout, int R)
{
    const int l = threadIdx.x & 63;
    const int wv = blockIdx.x * 4 + (threadIdx.x >> 6);
    const int nw = gridDim.x * 4;
    bf16x8 wf[8];
#pragma unroll
    for (int mb = 0; mb < 8; ++mb) wf[mb] = load_wfrag(W0, 128, 16 * mb, l);
    const f32x4 z = {0.f, 0.f, 0.f, 0.f};
    const int nt = (R + 15) >> 4;
    for (int t = wv; t < nt; t += nw) {
        bf16x8 xf = load_xfrag32(x, t * 16, l, R);
        const int node = t * 16 + (l & 15);
        const int fb = 4 * (l >> 4);
#pragma unroll
        for (int mb = 0; mb < 8; ++mb) {
            f32x4 c = __builtin_amdgcn_mfma_f32_16x16x32_bf16(wf[mb], xf, z, 0, 0, 0);
            short4 s = { f2bf(c[0]), f2bf(c[1]), f2bf(c[2]), f2bf(c[3]) };
            if (node < R) *(short4*)&Aout[(size_t)node * 128 + 16 * mb + fb] = s;
        }
    }
}

// ---------------------------------------------------------------------------
// kPQ: PQ = bf16(out @ [W1a | W1b])  [N,256]
// ---------------------------------------------------------------------------
__global__ __launch_bounds__(256) void kPQ(FP x, FP W1g, short* __restrict__ PQ, int R)
{
    const int l = threadIdx.x & 63;
    const int wv = blockIdx.x * 4 + (threadIdx.x >> 6);
    const int nw = gridDim.x * 4;
    bf16x8 wf[16];
#pragma unroll
    for (int mb = 0; mb < 8; ++mb) wf[mb] = load_wfrag(W1g, 128, 16 * mb, l);
#pragma unroll
    for (int mb = 0; mb < 8; ++mb) wf[8 + mb] = load_wfrag(W1g + 32 * 128, 128, 16 * mb, l);
    const f32x4 z = {0.f, 0.f, 0.f, 0.f};
    const int nt = (R + 15) >> 4;
    for (int t = wv; t < nt; t += nw) {
        bf16x8 xf = load_xfrag32(x, t * 16, l, R);
        const int node = t * 16 + (l & 15);
        const int fb = 4 * (l >> 4);
#pragma unroll
        for (int mb = 0; mb < 16; ++mb) {
            f32x4 c = __builtin_amdgcn_mfma_f32_16x16x32_bf16(wf[mb], xf, z, 0, 0, 0);
            short4 s = { f2bf(c[0]), f2bf(c[1]), f2bf(c[2]), f2bf(c[3]) };
            if (node < R) *(short4*)&PQ[(size_t)node * 256 + 16 * mb + fb] = s;
        }
    }
}

// ---------------------------------------------------------------------------
// kB: per 16-edge tile: Ee = ef@We via MFMA (C-layout: lane holds 32 feats of
// edge l&15); hi/hj = sp(A[i/j]+Ee); per-head att dot -> alpha0[E,4] + BN stats.
// ---------------------------------------------------------------------------
__global__ __launch_bounds__(256) void kB(
    FP ef, const int* __restrict__ eidx, const short* __restrict__ Abf,
    FP We, FP attg, float* __restrict__ alpha, float* __restrict__ bnstat, int E)
{
    __shared__ float attl[256];
    const int t = threadIdx.x;
    if (t < 64) ((float4*)attl)[t] = ((const float4*)attg)[t];
    __syncthreads();

    const int l = t & 63, q = l >> 4, e15 = l & 15;
    const int wv = blockIdx.x * 4 + (t >> 6), nw = gridDim.x * 4;
    bf16x8 wf[8];
#pragma unroll
    for (int mb = 0; mb < 8; ++mb) wf[mb] = load_wfrag(We, 128, 16 * mb, l);
    const f32x4 z = {0.f, 0.f, 0.f, 0.f};
    float bs[4] = {0,0,0,0}, bq2[4] = {0,0,0,0};

    const int nt = E >> 4;
    for (int tt = wv; tt < nt; tt += nw) {
        bf16x8 xf = load_xfrag32(ef, tt * 16, l, E);
        f32x4 acc[8];
#pragma unroll
        for (int mb = 0; mb < 8; ++mb)
            acc[mb] = __builtin_amdgcn_mfma_f32_16x16x32_bf16(wf[mb], xf, z, 0, 0, 0);

        const int e = tt * 16 + e15;
        const int i = eidx[e], j = eidx[E + e];
        float ph[4] = {0,0,0,0};
#pragma unroll
        for (int mb = 0; mb < 8; ++mb) {
            const short4 Ai = *(const short4*)&Abf[(size_t)i * 128 + 16 * mb + 4 * q];
            const short4 Aj = *(const short4*)&Abf[(size_t)j * 128 + 16 * mb + 4 * q];
            const int h = mb >> 1;
            const int c0 = (mb & 1) * 16 + 4 * q;
#pragma unroll
            for (int r = 0; r < 4; ++r) {
                const float ev = acc[mb][r];
                const float a1 = attl[h * 64 + c0 + r];
                const float a2 = attl[h * 64 + 32 + c0 + r];
                float aiv, ajv;
                aiv = (&Ai.x)[r]; ajv = (&Aj.x)[r];
                ph[h] += sp(bf2f((short)aiv) + ev) * a1 + sp(bf2f((short)ajv) + ev) * a2;
            }
        }
        float4 a0v;
#pragma unroll
        for (int h = 0; h < 4; ++h) {
            float v = ph[h];
            v += __shfl_xor(v, 16);
            v += __shfl_xor(v, 32);
            (&a0v.x)[h] = sp(v);
        }
        if (q == 0) {
            *(float4*)&alpha[(size_t)e * 4] = a0v;
#pragma unroll
            for (int h = 0; h < 4; ++h) {
                const float a0 = (&a0v.x)[h];
                bs[h] += a0; bq2[h] += a0 * a0;
            }
        }
    }
    // BN stat reduce across wave, one atomic set per wave
#pragma unroll
    for (int h = 0; h < 4; ++h) {
        float v = bs[h], w = bq2[h];
#pragma unroll
        for (int d = 1; d < 64; d <<= 1) { v += __shfl_xor(v, d); w += __shfl_xor(w, d); }
        if (l == 0) { atomicAdd(&bnstat[h], v); atomicAdd(&bnstat[4 + h], w); }
    }
}

// k2: finalize BN scale/shift
__global__ void k2_bn(const float* __restrict__ bnstat, FP gam, FP bet,
                      float* __restrict__ bnsc, int E)
{
    const int t = threadIdx.x;
    if (t < 4) {
        const float inv = 1.f / (float)E;
        const float mu  = bnstat[t] * inv;
        const float var = bnstat[4 + t] * inv - mu * mu;
        const float scl = gam[t] * rsqrtf(var + 1e-5f);
        bnsc[t] = scl;
        bnsc[4 + t] = bet[t] - mu * scl;
    }
}

// k3: alpha1 = sp(scale*alpha0+shift); segment max via uint atomicMax (alpha1>0)
__global__ __launch_bounds__(256) void k3_bnmax(
    float* __restrict__ alpha, const int* __restrict__ eidx,
    unsigned int* __restrict__ mbuf, const float* __restrict__ bnsc, int E)
{
    const int t = blockIdx.x * 256 + threadIdx.x;
    if (t >= 4 * E) return;
    const int e = t >> 2, h = t & 3;
    const float a1 = sp(bnsc[h] * alpha[t] + bnsc[4 + h]);
    alpha[t] = a1;
    atomicMax(&mbuf[eidx[e] * 4 + h], __float_as_uint(a1));
}

// k4: ex = exp(alpha1 - m[row]); segment sum
__global__ __launch_bounds__(256) void k4_exps(
    float* __restrict__ alpha, const int* __restrict__ eidx,
    const float* __restrict__ mbuf, float* __restrict__ sbuf, int E)
{
    const int t = blockIdx.x * 256 + threadIdx.x;
    if (t >= 4 * E) return;
    const int e = t >> 2, h = t & 3;
    const float ex = expf(alpha[t] - mbuf[eidx[e] * 4 + h]);
    alpha[t] = ex;
    atomicAdd(&sbuf[eidx[e] * 4 + h], ex);
}

// ---------------------------------------------------------------------------
// kmsg: recompute Ee via MFMA; hj = sp(A[j]+Ee); contrib = 0.25*sum_h af_h*hj
// -> atomicAdd into outacc[row,32]
// ---------------------------------------------------------------------------
__global__ __launch_bounds__(256) void kmsg(
    FP ef, const int* __restrict__ eidx, const short* __restrict__ Abf,
    FP We, const float* __restrict__ alpha, const float* __restrict__ sbuf,
    float* __restrict__ outacc, int E)
{
    const int l = threadIdx.x & 63, q = l >> 4, e15 = l & 15;
    const int wv = blockIdx.x * 4 + (threadIdx.x >> 6), nw = gridDim.x * 4;
    bf16x8 wf[8];
#pragma unroll
    for (int mb = 0; mb < 8; ++mb) wf[mb] = load_wfrag(We, 128, 16 * mb, l);
    const f32x4 z = {0.f, 0.f, 0.f, 0.f};

    const int nt = E >> 4;
    for (int tt = wv; tt < nt; tt += nw) {
        bf16x8 xf = load_xfrag32(ef, tt * 16, l, E);
        f32x4 acc[8];
#pragma unroll
        for (int mb = 0; mb < 8; ++mb)
            acc[mb] = __builtin_amdgcn_mfma_f32_16x16x32_bf16(wf[mb], xf, z, 0, 0, 0);

        const int e = tt * 16 + e15;
        const int i = eidx[e], j = eidx[E + e];
        const float4 a4 = *(const float4*)&alpha[(size_t)e * 4];
        const float4 s4 = *(const float4*)&sbuf[(size_t)i * 4];
        float af[4];
#pragma unroll
        for (int h = 0; h < 4; ++h) af[h] = (&a4.x)[h] / ((&s4.x)[h] + 1e-16f);

        float cl[4] = {0,0,0,0}, ch[4] = {0,0,0,0};
#pragma unroll
        for (int mb = 0; mb < 8; ++mb) {
            const short4 Aj = *(const short4*)&Abf[(size_t)j * 128 + 16 * mb + 4 * q];
            const int h = mb >> 1;
#pragma unroll
            for (int r = 0; r < 4; ++r) {
                const float v = sp(bf2f((&Aj.x)[r]) + acc[mb][r]) * af[h];
                if (mb & 1) ch[r] += v; else cl[r] += v;
            }
        }
#pragma unroll
        for (int r = 0; r < 4; ++r) {
            atomicAdd(&outacc[(size_t)i * 32 + 4 * q + r],      0.25f * cl[r]);
            atomicAdd(&outacc[(size_t)i * 32 + 16 + 4 * q + r], 0.25f * ch[r]);
        }
    }
}

// kout: out += bias (acc accumulated in place in d_out)
__global__ __launch_bounds__(256) void kout(float* __restrict__ outp, FP bias, int N)
{
    const int t = blockIdx.x * 256 + threadIdx.x;
    if (t < N * 32) outp[t] += bias[t & 31];
}

// ---------------------------------------------------------------------------
// kG2: R = ef@W1c via MFMA -> LDS; h = silu(P[row]+Q[col]+R+b1) in B-frag
// layout; eout = silu(h@W2 + b2) via MFMA.
// ---------------------------------------------------------------------------
__global__ __launch_bounds__(256) void kG2(
    FP ef, const int* __restrict__ eidx, const short* __restrict__ PQ,
    FP W1c, FP W2, FP b1g, FP b2g, float* __restrict__ eout, int E)
{
    __shared__ float b1l[128];
    __shared__ float b2l[32];
    __shared__ short Rl[4][16 * 132];
    const int t = threadIdx.x;
    if (t < 128) b1l[t] = b1g[t];
    if (t < 32)  b2l[t] = b2g[t];
    __syncthreads();

    const int l = t & 63, q = l >> 4, e15 = l & 15, wvb = t >> 6;
    short* Rw = &Rl[wvb][0];
    bf16x8 wr[8];
#pragma unroll
    for (int mb = 0; mb < 8; ++mb) wr[mb] = load_wfrag(W1c, 128, 16 * mb, l);
    bf16x8 w2f[4][2];
#pragma unroll
    for (int kc = 0; kc < 4; ++kc)
#pragma unroll
        for (int m2 = 0; m2 < 2; ++m2)
            w2f[kc][m2] = load_wfrag(W2 + 32 * kc * 32, 32, 16 * m2, l);
    const f32x4 z = {0.f, 0.f, 0.f, 0.f};

    const int wv = blockIdx.x * 4 + wvb, nw = gridDim.x * 4, nt = E >> 4;
    for (int tt = wv; tt < nt; tt += nw) {
        bf16x8 xf = load_xfrag32(ef, tt * 16, l, E);
#pragma unroll
        for (int mb = 0; mb < 8; ++mb) {
            f32x4 c = __builtin_amdgcn_mfma_f32_16x16x32_bf16(wr[mb], xf, z, 0, 0, 0);
            short4 s = { f2bf(c[0]), f2bf(c[1]), f2bf(c[2]), f2bf(c[3]) };
            *(short4*)&Rw[e15 * 132 + 16 * mb + 4 * q] = s;   // wave-internal LDS, in-order DS pipe
        }
        const int e = tt * 16 + e15;
        const int ri = eidx[e], ci = eidx[E + e];
        const short* Pp = &PQ[(size_t)ri * 256];
        const short* Qp = &PQ[(size_t)ci * 256 + 128];

        f32x4 oc0 = z, oc1 = z;
#pragma unroll
        for (int kc = 0; kc < 4; ++kc) {
            const int o = 32 * kc + 8 * q;
            const short4 r0 = *(const short4*)&Rw[e15 * 132 + o];
            const short4 r1 = *(const short4*)&Rw[e15 * 132 + o + 4];
            const short4 p0 = *(const short4*)&Pp[o];
            const short4 p1 = *(const short4*)&Pp[o + 4];
            const short4 q0 = *(const short4*)&Qp[o];
            const short4 q1 = *(const short4*)&Qp[o + 4];
            const float4 bA = *(const float4*)&b1l[o];
            const float4 bB = *(const float4*)&b1l[o + 4];
            bf16x8 hf;
#pragma unroll
            for (int jj = 0; jj < 4; ++jj) {
                hf[jj]     = f2bf(silu_f(bf2f((&r0.x)[jj]) + bf2f((&p0.x)[jj]) + bf2f((&q0.x)[jj]) + (&bA.x)[jj]));
                hf[4 + jj] = f2bf(silu_f(bf2f((&r1.x)[jj]) + bf2f((&p1.x)[jj]) + bf2f((&q1.x)[jj]) + (&bB.x)[jj]));
            }
            oc0 = __builtin_amdgcn_mfma_f32_16x16x32_bf16(w2f[kc][0], hf, oc0, 0, 0, 0);
            oc1 = __builtin_amdgcn_mfma_f32_16x16x32_bf16(w2f[kc][1], hf, oc1, 0, 0, 0);
        }
        float4 o0, o1;
#pragma unroll
        for (int r = 0; r < 4; ++r) {
            (&o0.x)[r] = silu_f(oc0[r] + b2l[4 * q + r]);
            (&o1.x)[r] = silu_f(oc1[r] + b2l[16 + 4 * q + r]);
        }
        *(float4*)&eout[(size_t)e * 32 + 4 * q] = o0;
        *(float4*)&eout[(size_t)e * 32 + 16 + 4 * q] = o1;
    }
}

extern "C" void kernel_launch(void* const* d_in, const int* in_sizes, int n_in,
                              void* d_out, int out_size, void* d_ws, size_t ws_size,
                              hipStream_t stream)
{
    const float* atom = (const float*)d_in[0];
    const int*   eidx = (const int*)d_in[1];
    const float* efea = (const float*)d_in[2];
    const float* Wg   = (const float*)d_in[6];
    const float* attg = (const float*)d_in[7];
    const float* bias = (const float*)d_in[8];
    const float* gam  = (const float*)d_in[9];
    const float* bet  = (const float*)d_in[10];
    const float* W1g  = (const float*)d_in[11];
    const float* b1g  = (const float*)d_in[12];
    const float* W2g  = (const float*)d_in[13];
    const float* b2g  = (const float*)d_in[14];

    const int N = in_sizes[0] / 32;
    const int E = in_sizes[2] / 32;

    // workspace: mbuf[4N] sbuf[4N] bnstat[8] bnsc[8] PQ[N*256 bf16]
    float* ws     = (float*)d_ws;
    float* mbuf   = ws;
    float* sbuf   = ws + (size_t)4 * N;
    float* bnstat = ws + (size_t)8 * N;
    float* bnsc   = bnstat + 8;
    short* PQ     = (short*)(ws + (size_t)8 * N + 16);

    // d_out: [out N*32 f32][eout E*32 f32]; eout region doubles as scratch
    float* outp = (float*)d_out;
    float* scratch = outp + (size_t)N * 32;
    short* Abf  = (short*)scratch;                   // N*128 bf16 = N*64 f32 slots
    float* alpha = scratch + (size_t)N * 64;         // 4E f32
    float* eout = scratch;                           // written last by kG2

    hipMemsetAsync(outp, 0, (size_t)N * 32 * sizeof(float), stream);       // msg accumulator
    hipMemsetAsync(ws, 0, ((size_t)8 * N + 16) * sizeof(float), stream);   // mbuf,sbuf,bnstat

    const int n4e = 4 * E;
    kA  <<<256, 256, 0, stream>>>(atom, Wg, Abf, N);
    kB  <<<2048, 256, 0, stream>>>(efea, eidx, Abf, Wg + 32 * 128, attg, alpha, bnstat, E);
    k2_bn<<<1, 64, 0, stream>>>(bnstat, gam, bet, bnsc, E);
    k3_bnmax<<<(n4e + 255) / 256, 256, 0, stream>>>(alpha, eidx, (unsigned int*)mbuf, bnsc, E);
    k4_exps <<<(n4e + 255) / 256, 256, 0, stream>>>(alpha, eidx, mbuf, sbuf, E);
    kmsg<<<2048, 256, 0, stream>>>(efea, eidx, Abf, Wg + 32 * 128, alpha, sbuf, outp, E);
    kout<<<(N * 32 + 255) / 256, 256, 0, stream>>>(outp, bias, N);
    kPQ <<<256, 256, 0, stream>>>(outp, W1g, PQ, N);
    kG2 <<<2048, 256, 0, stream>>>(efea, eidx, PQ, W1g + 64 * 128, W2g, b1g, b2g, eout, E);
}

// Round 4
// 1449.576 us; speedup vs baseline: 2.6955x; 1.1590x over previous
//
#include <hip/hip_runtime.h>

typedef __attribute__((ext_vector_type(8))) short bf16x8;
typedef __attribute__((ext_vector_type(4))) float f32x4;

#define FP const float* __restrict__

__device__ __forceinline__ short f2bf(float f) {
    unsigned u = __float_as_uint(f);
    u += 0x7fffu + ((u >> 16) & 1u);
    return (short)(u >> 16);
}
__device__ __forceinline__ float bf2f(short s) {
    return __uint_as_float(((unsigned)(unsigned short)s) << 16);
}
// branch-free fast transcendentals (v_exp_f32 / v_log_f32 / v_rcp_f32)
__device__ __forceinline__ float fexp(float x) {       // e^x
    return exp2f(1.44269504f * x);
}
__device__ __forceinline__ float sp(float x) {         // softplus
    const float t = exp2f(-1.44269504f * fabsf(x));
    return fmaxf(x, 0.f) + 0.69314718f * log2f(1.f + t);
}
__device__ __forceinline__ float silu_f(float x) {
    const float d = 1.f + exp2f(-1.44269504f * x);
    return x * __builtin_amdgcn_rcpf(d);
}

// A-operand = W^T tile: lane l holds W[k, c0+(l&15)], k = 8*(l>>4)+j. W is [32+,ld] f32.
__device__ __forceinline__ bf16x8 load_wfrag(FP w, int ld, int c0, int l) {
    const int c = c0 + (l & 15);
    const int k0 = 8 * (l >> 4);
    bf16x8 f;
#pragma unroll
    for (int j = 0; j < 8; ++j) f[j] = f2bf(w[(k0 + j) * ld + c]);
    return f;
}
// B-operand = x^T tile: lane l holds x[r0+(l&15), 8*(l>>4)+j]; x is [R,32] f32 row-major.
__device__ __forceinline__ bf16x8 load_xfrag32(FP x, int r0, int l, int R) {
    int row = r0 + (l & 15);
    row = row < R ? row : R - 1;
    const float* p = x + (size_t)row * 32 + 8 * (l >> 4);
    const float4 a = *(const float4*)p;
    const float4 b = *(const float4*)(p + 4);
    bf16x8 f;
    f[0]=f2bf(a.x); f[1]=f2bf(a.y); f[2]=f2bf(a.z); f[3]=f2bf(a.w);
    f[4]=f2bf(b.x); f[5]=f2bf(b.y); f[6]=f2bf(b.z); f[7]=f2bf(b.w);
    return f;
}

// ---------------------------------------------------------------------------
// kA: A = bf16(atom @ Wa) [N,128], stored PERMUTED: row n, short index
//     32*q + 4*mb + r  (q=lane>>4, feature f = 16*mb + 4*q + r)
// so that kB/kmsg gather one head's 8 lane-features as a single 16B load.
// ---------------------------------------------------------------------------
__global__ __launch_bounds__(256) void kA(FP x, FP W0, short* __restrict__ Aout, int R)
{
    const int l = threadIdx.x & 63;
    const int wv = blockIdx.x * 4 + (threadIdx.x >> 6);
    const int nw = gridDim.x * 4;
    bf16x8 wf[8];
#pragma unroll
    for (int mb = 0; mb < 8; ++mb) wf[mb] = load_wfrag(W0, 128, 16 * mb, l);
    const f32x4 z = {0.f, 0.f, 0.f, 0.f};
    const int nt = (R + 15) >> 4;
    for (int t = wv; t < nt; t += nw) {
        bf16x8 xf = load_xfrag32(x, t * 16, l, R);
        const int node = t * 16 + (l & 15);
        const int q = l >> 4;
#pragma unroll
        for (int mb = 0; mb < 8; ++mb) {
            f32x4 c = __builtin_amdgcn_mfma_f32_16x16x32_bf16(wf[mb], xf, z, 0, 0, 0);
            short4 s = { f2bf(c[0]), f2bf(c[1]), f2bf(c[2]), f2bf(c[3]) };
            if (node < R) *(short4*)&Aout[(size_t)node * 128 + 32 * q + 4 * mb] = s;
        }
    }
}

// ---------------------------------------------------------------------------
// kPQ: PQ = bf16(out @ [W1a | W1b])  [N,256], natural feature order
// ---------------------------------------------------------------------------
__global__ __launch_bounds__(256) void kPQ(FP x, FP W1g, short* __restrict__ PQ, int R)
{
    const int l = threadIdx.x & 63;
    const int wv = blockIdx.x * 4 + (threadIdx.x >> 6);
    const int nw = gridDim.x * 4;
    bf16x8 wf[16];
#pragma unroll
    for (int mb = 0; mb < 8; ++mb) wf[mb] = load_wfrag(W1g, 128, 16 * mb, l);
#pragma unroll
    for (int mb = 0; mb < 8; ++mb) wf[8 + mb] = load_wfrag(W1g + 32 * 128, 128, 16 * mb, l);
    const f32x4 z = {0.f, 0.f, 0.f, 0.f};
    const int nt = (R + 15) >> 4;
    for (int t = wv; t < nt; t += nw) {
        bf16x8 xf = load_xfrag32(x, t * 16, l, R);
        const int node = t * 16 + (l & 15);
        const int fb = 4 * (l >> 4);
#pragma unroll
        for (int mb = 0; mb < 16; ++mb) {
            f32x4 c = __builtin_amdgcn_mfma_f32_16x16x32_bf16(wf[mb], xf, z, 0, 0, 0);
            short4 s = { f2bf(c[0]), f2bf(c[1]), f2bf(c[2]), f2bf(c[3]) };
            if (node < R) *(short4*)&PQ[(size_t)node * 256 + 16 * mb + fb] = s;
        }
    }
}

// ---------------------------------------------------------------------------
// kB: Ee = ef@We via MFMA; hi/hj = sp(A[i/j]+Ee); att dot -> alpha0 + BN stats
// ---------------------------------------------------------------------------
__global__ __launch_bounds__(256) void kB(
    FP ef, const int* __restrict__ eidx, const short* __restrict__ Abf,
    FP We, FP attg, float* __restrict__ alpha, float* __restrict__ bnstat, int E)
{
    __shared__ float attl[256];
    const int t = threadIdx.x;
    if (t < 64) ((float4*)attl)[t] = ((const float4*)attg)[t];
    __syncthreads();

    const int l = t & 63, q = l >> 4, e15 = l & 15;
    const int wv = blockIdx.x * 4 + (t >> 6), nw = gridDim.x * 4;
    bf16x8 wf[8];
#pragma unroll
    for (int mb = 0; mb < 8; ++mb) wf[mb] = load_wfrag(We, 128, 16 * mb, l);
    const f32x4 z = {0.f, 0.f, 0.f, 0.f};
    float bs[4] = {0,0,0,0}, bq2[4] = {0,0,0,0};

    const int nt = E >> 4;
    for (int tt = wv; tt < nt; tt += nw) {
        bf16x8 xf = load_xfrag32(ef, tt * 16, l, E);
        f32x4 acc[8];
#pragma unroll
        for (int mb = 0; mb < 8; ++mb)
            acc[mb] = __builtin_amdgcn_mfma_f32_16x16x32_bf16(wf[mb], xf, z, 0, 0, 0);

        const int e = tt * 16 + e15;
        const int i = eidx[e], j = eidx[E + e];
        float ph[4] = {0,0,0,0};
#pragma unroll
        for (int p = 0; p < 4; ++p) {
            const bf16x8 Ai = *(const bf16x8*)&Abf[(size_t)i * 128 + 32 * q + 8 * p];
            const bf16x8 Aj = *(const bf16x8*)&Abf[(size_t)j * 128 + 32 * q + 8 * p];
#pragma unroll
            for (int jj = 0; jj < 8; ++jj) {
                const float ev = acc[2 * p + (jj >> 2)][jj & 3];
                const int c = (jj >> 2) * 16 + 4 * q + (jj & 3);
                ph[p] += sp(bf2f(Ai[jj]) + ev) * attl[p * 64 + c]
                       + sp(bf2f(Aj[jj]) + ev) * attl[p * 64 + 32 + c];
            }
        }
        float4 a0v;
#pragma unroll
        for (int h = 0; h < 4; ++h) {
            float v = ph[h];
            v += __shfl_xor(v, 16);
            v += __shfl_xor(v, 32);
            (&a0v.x)[h] = sp(v);
        }
        if (q == 0) {
            *(float4*)&alpha[(size_t)e * 4] = a0v;
#pragma unroll
            for (int h = 0; h < 4; ++h) {
                const float a0 = (&a0v.x)[h];
                bs[h] += a0; bq2[h] += a0 * a0;
            }
        }
    }
#pragma unroll
    for (int h = 0; h < 4; ++h) {
        float v = bs[h], w = bq2[h];
#pragma unroll
        for (int d = 1; d < 64; d <<= 1) { v += __shfl_xor(v, d); w += __shfl_xor(w, d); }
        if (l == 0) { atomicAdd(&bnstat[h], v); atomicAdd(&bnstat[4 + h], w); }
    }
}

// k2: finalize BN scale/shift
__global__ void k2_bn(const float* __restrict__ bnstat, FP gam, FP bet,
                      float* __restrict__ bnsc, int E)
{
    const int t = threadIdx.x;
    if (t < 4) {
        const float inv = 1.f / (float)E;
        const float mu  = bnstat[t] * inv;
        const float var = bnstat[4 + t] * inv - mu * mu;
        const float scl = gam[t] * rsqrtf(var + 1e-5f);
        bnsc[t] = scl;
        bnsc[4 + t] = bet[t] - mu * scl;
    }
}

// k3: alpha1 = sp(scale*alpha0+shift); segment max via uint atomicMax (alpha1>0)
__global__ __launch_bounds__(256) void k3_bnmax(
    float* __restrict__ alpha, const int* __restrict__ eidx,
    unsigned int* __restrict__ mbuf, const float* __restrict__ bnsc, int E)
{
    const int t = blockIdx.x * 256 + threadIdx.x;
    if (t >= 4 * E) return;
    const int e = t >> 2, h = t & 3;
    const float a1 = sp(bnsc[h] * alpha[t] + bnsc[4 + h]);
    alpha[t] = a1;
    atomicMax(&mbuf[eidx[e] * 4 + h], __float_as_uint(a1));
}

// k4: ex = exp(alpha1 - m[row]); segment sum
__global__ __launch_bounds__(256) void k4_exps(
    float* __restrict__ alpha, const int* __restrict__ eidx,
    const float* __restrict__ mbuf, float* __restrict__ sbuf, int E)
{
    const int t = blockIdx.x * 256 + threadIdx.x;
    if (t >= 4 * E) return;
    const int e = t >> 2, h = t & 3;
    const float ex = fexp(alpha[t] - mbuf[eidx[e] * 4 + h]);
    alpha[t] = ex;
    atomicAdd(&sbuf[eidx[e] * 4 + h], ex);
}

// ---------------------------------------------------------------------------
// kmsg: recompute Ee via MFMA; hj = sp(A[j]+Ee); out[i] += 0.25*sum_h af_h*hj
// ---------------------------------------------------------------------------
__global__ __launch_bounds__(256) void kmsg(
    FP ef, const int* __restrict__ eidx, const short* __restrict__ Abf,
    FP We, const float* __restrict__ alpha, const float* __restrict__ sbuf,
    float* __restrict__ outacc, int E)
{
    const int l = threadIdx.x & 63, q = l >> 4, e15 = l & 15;
    const int wv = blockIdx.x * 4 + (threadIdx.x >> 6), nw = gridDim.x * 4;
    bf16x8 wf[8];
#pragma unroll
    for (int mb = 0; mb < 8; ++mb) wf[mb] = load_wfrag(We, 128, 16 * mb, l);
    const f32x4 z = {0.f, 0.f, 0.f, 0.f};

    const int nt = E >> 4;
    for (int tt = wv; tt < nt; tt += nw) {
        bf16x8 xf = load_xfrag32(ef, tt * 16, l, E);
        f32x4 acc[8];
#pragma unroll
        for (int mb = 0; mb < 8; ++mb)
            acc[mb] = __builtin_amdgcn_mfma_f32_16x16x32_bf16(wf[mb], xf, z, 0, 0, 0);

        const int e = tt * 16 + e15;
        const int i = eidx[e], j = eidx[E + e];
        const float4 a4 = *(const float4*)&alpha[(size_t)e * 4];
        const float4 s4 = *(const float4*)&sbuf[(size_t)i * 4];
        float af[4];
#pragma unroll
        for (int h = 0; h < 4; ++h)
            af[h] = (&a4.x)[h] * __builtin_amdgcn_rcpf((&s4.x)[h] + 1e-16f);

        float c4[8] = {0,0,0,0,0,0,0,0};
#pragma unroll
        for (int p = 0; p < 4; ++p) {
            const bf16x8 Aj = *(const bf16x8*)&Abf[(size_t)j * 128 + 32 * q + 8 * p];
#pragma unroll
            for (int jj = 0; jj < 8; ++jj)
                c4[jj] += sp(bf2f(Aj[jj]) + acc[2 * p + (jj >> 2)][jj & 3]) * af[p];
        }
#pragma unroll
        for (int jj = 0; jj < 8; ++jj) {
            const int c = (jj >> 2) * 16 + 4 * q + (jj & 3);
            atomicAdd(&outacc[(size_t)i * 32 + c], 0.25f * c4[jj]);
        }
    }
}

// kout: out += bias (acc accumulated in place in d_out)
__global__ __launch_bounds__(256) void kout(float* __restrict__ outp, FP bias, int N)
{
    const int t = blockIdx.x * 256 + threadIdx.x;
    if (t < N * 32) outp[t] += bias[t & 31];
}

// ---------------------------------------------------------------------------
// kG2: R = ef@W1c via MFMA -> LDS; h = silu(P[row]+Q[col]+R+b1) in B-frag
// layout; eout = silu(h@W2 + b2) via MFMA.
// ---------------------------------------------------------------------------
__global__ __launch_bounds__(256) void kG2(
    FP ef, const int* __restrict__ eidx, const short* __restrict__ PQ,
    FP W1c, FP W2, FP b1g, FP b2g, float* __restrict__ eout, int E)
{
    __shared__ float b1l[128];
    __shared__ float b2l[32];
    __shared__ short Rl[4][16 * 132];
    const int t = threadIdx.x;
    if (t < 128) b1l[t] = b1g[t];
    if (t < 32)  b2l[t] = b2g[t];
    __syncthreads();

    const int l = t & 63, q = l >> 4, e15 = l & 15, wvb = t >> 6;
    short* Rw = &Rl[wvb][0];
    bf16x8 wr[8];
#pragma unroll
    for (int mb = 0; mb < 8; ++mb) wr[mb] = load_wfrag(W1c, 128, 16 * mb, l);
    bf16x8 w2f[4][2];
#pragma unroll
    for (int kc = 0; kc < 4; ++kc)
#pragma unroll
        for (int m2 = 0; m2 < 2; ++m2)
            w2f[kc][m2] = load_wfrag(W2 + 32 * kc * 32, 32, 16 * m2, l);
    const f32x4 z = {0.f, 0.f, 0.f, 0.f};

    const int wv = blockIdx.x * 4 + wvb, nw = gridDim.x * 4, nt = E >> 4;
    for (int tt = wv; tt < nt; tt += nw) {
        bf16x8 xf = load_xfrag32(ef, tt * 16, l, E);
#pragma unroll
        for (int mb = 0; mb < 8; ++mb) {
            f32x4 c = __builtin_amdgcn_mfma_f32_16x16x32_bf16(wr[mb], xf, z, 0, 0, 0);
            short4 s = { f2bf(c[0]), f2bf(c[1]), f2bf(c[2]), f2bf(c[3]) };
            *(short4*)&Rw[e15 * 132 + 16 * mb + 4 * q] = s;   // wave-internal LDS
        }
        const int e = tt * 16 + e15;
        const int ri = eidx[e], ci = eidx[E + e];
        const short* Pp = &PQ[(size_t)ri * 256];
        const short* Qp = &PQ[(size_t)ci * 256 + 128];

        f32x4 oc0 = z, oc1 = z;
#pragma unroll
        for (int kc = 0; kc < 4; ++kc) {
            const int o = 32 * kc + 8 * q;
            const short4 r0 = *(const short4*)&Rw[e15 * 132 + o];
            const short4 r1 = *(const short4*)&Rw[e15 * 132 + o + 4];
            const short4 p0 = *(const short4*)&Pp[o];
            const short4 p1 = *(const short4*)&Pp[o + 4];
            const short4 q0 = *(const short4*)&Qp[o];
            const short4 q1 = *(const short4*)&Qp[o + 4];
            const float4 bA = *(const float4*)&b1l[o];
            const float4 bB = *(const float4*)&b1l[o + 4];
            bf16x8 hf;
#pragma unroll
            for (int jj = 0; jj < 4; ++jj) {
                hf[jj]     = f2bf(silu_f(bf2f((&r0.x)[jj]) + bf2f((&p0.x)[jj]) + bf2f((&q0.x)[jj]) + (&bA.x)[jj]));
                hf[4 + jj] = f2bf(silu_f(bf2f((&r1.x)[jj]) + bf2f((&p1.x)[jj]) + bf2f((&q1.x)[jj]) + (&bB.x)[jj]));
            }
            oc0 = __builtin_amdgcn_mfma_f32_16x16x32_bf16(w2f[kc][0], hf, oc0, 0, 0, 0);
            oc1 = __builtin_amdgcn_mfma_f32_16x16x32_bf16(w2f[kc][1], hf, oc1, 0, 0, 0);
        }
        float4 o0, o1;
#pragma unroll
        for (int r = 0; r < 4; ++r) {
            (&o0.x)[r] = silu_f(oc0[r] + b2l[4 * q + r]);
            (&o1.x)[r] = silu_f(oc1[r] + b2l[16 + 4 * q + r]);
        }
        *(float4*)&eout[(size_t)e * 32 + 4 * q] = o0;
        *(float4*)&eout[(size_t)e * 32 + 16 + 4 * q] = o1;
    }
}

extern "C" void kernel_launch(void* const* d_in, const int* in_sizes, int n_in,
                              void* d_out, int out_size, void* d_ws, size_t ws_size,
                              hipStream_t stream)
{
    const float* atom = (const float*)d_in[0];
    const int*   eidx = (const int*)d_in[1];
    const float* efea = (const float*)d_in[2];
    const float* Wg   = (const float*)d_in[6];
    const float* attg = (const float*)d_in[7];
    const float* bias = (const float*)d_in[8];
    const float* gam  = (const float*)d_in[9];
    const float* bet  = (const float*)d_in[10];
    const float* W1g  = (const float*)d_in[11];
    const float* b1g  = (const float*)d_in[12];
    const float* W2g  = (const float*)d_in[13];
    const float* b2g  = (const float*)d_in[14];

    const int N = in_sizes[0] / 32;
    const int E = in_sizes[2] / 32;

    // workspace: mbuf[4N] sbuf[4N] bnstat[8] bnsc[8] PQ[N*256 bf16]
    float* ws     = (float*)d_ws;
    float* mbuf   = ws;
    float* sbuf   = ws + (size_t)4 * N;
    float* bnstat = ws + (size_t)8 * N;
    float* bnsc   = bnstat + 8;
    short* PQ     = (short*)(ws + (size_t)8 * N + 16);

    // d_out: [out N*32 f32][eout E*32 f32]; eout region doubles as scratch
    float* outp = (float*)d_out;
    float* scratch = outp + (size_t)N * 32;
    short* Abf  = (short*)scratch;                   // N*128 bf16
    float* alpha = scratch + (size_t)N * 64;         // 4E f32
    float* eout = scratch;                           // written last by kG2

    hipMemsetAsync(outp, 0, (size_t)N * 32 * sizeof(float), stream);       // msg accumulator
    hipMemsetAsync(ws, 0, ((size_t)8 * N + 16) * sizeof(float), stream);   // mbuf,sbuf,bnstat

    const int n4e = 4 * E;
    kA  <<<256, 256, 0, stream>>>(atom, Wg, Abf, N);
    kB  <<<2048, 256, 0, stream>>>(efea, eidx, Abf, Wg + 32 * 128, attg, alpha, bnstat, E);
    k2_bn<<<1, 64, 0, stream>>>(bnstat, gam, bet, bnsc, E);
    k3_bnmax<<<(n4e + 255) / 256, 256, 0, stream>>>(alpha, eidx, (unsigned int*)mbuf, bnsc, E);
    k4_exps <<<(n4e + 255) / 256, 256, 0, stream>>>(alpha, eidx, mbuf, sbuf, E);
    kmsg<<<2048, 256, 0, stream>>>(efea, eidx, Abf, Wg + 32 * 128, alpha, sbuf, outp, E);
    kout<<<(N * 32 + 255) / 256, 256, 0, stream>>>(outp, bias, N);
    kPQ <<<256, 256, 0, stream>>>(outp, W1g, PQ, N);
    kG2 <<<2048, 256, 0, stream>>>(efea, eidx, PQ, W1g + 64 * 128, W2g, b1g, b2g, eout, E);
}